// Round 14
// baseline (159.832 us; speedup 1.0000x reference)
//
#include <hip/hip_runtime.h>
#include <stdint.h>

#define D_    512
#define H_    2
#define HD_   256
#define B_    16
#define S_    1194
#define MTOK  19104          // B_*S_
#define MPAD  19200          // 150*128
#define SPAD  1216           // 19*64 = 38*32
#define NQKV  1536
#define NKT   38             // kv tiles of 32 (global layout granularity)
#define LOG2E 1.44269504088896340736f

typedef unsigned short u16;
typedef __attribute__((ext_vector_type(8))) short bf16x8;   // 8 bf16 = 4 VGPR
typedef __attribute__((ext_vector_type(4))) float f32x4;

__device__ inline u16 f2bf(float x) {
  union { float f; unsigned u; } c; c.f = x;
  unsigned r = c.u + 0x7fffu + ((c.u >> 16) & 1u);  // RNE
  return (u16)(r >> 16);
}

// async global->LDS, 16B per lane. LDS dest is wave-uniform base (HW adds
// lane*16); global src per-lane, CONTIGUOUS: 1 instr = 1KB sequential.
__device__ inline void async_copy16(void* lds, const void* g) {
  __builtin_amdgcn_global_load_lds(
      (__attribute__((address_space(1))) void*)(g),
      (__attribute__((address_space(3))) void*)(lds),
      16, 0, 0);
}

// ---------------------------------------------------------------------------
// Kernel 1 (unchanged): X/W -> frag-major bf16.
// ---------------------------------------------------------------------------
__global__ void convert_kernel(const float* __restrict__ X,
                               const float* __restrict__ Wqkv,
                               const float* __restrict__ Wout,
                               u16* __restrict__ Xf,
                               u16* __restrict__ Wqf,
                               u16* __restrict__ Wof) {
  const int NXG = MPAD * 64;
  const int NQG = 12 * 8 * 16 * 64;
  const int NOG = 4 * 8 * 16 * 64;
  const int TOT = NXG + NQG + NOG;
  int stride = gridDim.x * blockDim.x;
  for (int g = blockIdx.x * blockDim.x + threadIdx.x; g < TOT; g += stride) {
    if (g < NXG) {
      int lane = g & 63, f = (g >> 6) & 15, kt = (g >> 10) & 7, mt = g >> 13;
      int i = mt * 128 + (f & 7) * 16 + (lane & 15);
      int k = kt * 64 + (f >> 3) * 32 + (lane >> 4) * 8;
      bf16x8 o;
      if (i < MTOK) {
        f32x4 v0 = *(const f32x4*)&X[(size_t)i * 512 + k];
        f32x4 v1 = *(const f32x4*)&X[(size_t)i * 512 + k + 4];
#pragma unroll
        for (int e = 0; e < 4; ++e) { o[e] = (short)f2bf(v0[e]); o[4 + e] = (short)f2bf(v1[e]); }
      } else {
#pragma unroll
        for (int e = 0; e < 8; ++e) o[e] = 0;
      }
      *(bf16x8*)&Xf[(size_t)g * 8] = o;
    } else if (g < NXG + NQG) {
      int gg = g - NXG;
      int lane = gg & 63, f = (gg >> 6) & 15, kt = (gg >> 10) & 7, nt = gg >> 13;
      int j = nt * 128 + (f & 7) * 16 + (lane & 15);
      int k = kt * 64 + (f >> 3) * 32 + (lane >> 4) * 8;
      bf16x8 o;
#pragma unroll
      for (int e = 0; e < 8; ++e) o[e] = (short)f2bf(Wqkv[(size_t)(k + e) * NQKV + j]);
      *(bf16x8*)&Wqf[(size_t)gg * 8] = o;
    } else {
      int gg = g - NXG - NQG;
      int lane = gg & 63, f = (gg >> 6) & 15, kt = (gg >> 10) & 7, nt = gg >> 13;
      int j = nt * 128 + (f & 7) * 16 + (lane & 15);
      int k = kt * 64 + (f >> 3) * 32 + (lane >> 4) * 8;
      bf16x8 o;
#pragma unroll
      for (int e = 0; e < 8; ++e) o[e] = (short)f2bf(Wout[(size_t)(k + e) * 512 + j]);
      *(bf16x8*)&Wof[(size_t)gg * 8] = o;
    }
  }
}

// ---------------------------------------------------------------------------
// GEMM v2 (unchanged from round 10): m97 single-buffer schedule.
// ---------------------------------------------------------------------------
template<int MODE>
__global__ __launch_bounds__(256, 2) void gemm_kernel(
    const u16* __restrict__ Af, const u16* __restrict__ Bf,
    const float* __restrict__ bias, int nb,
    u16* __restrict__ Qb, u16* __restrict__ Kf, u16* __restrict__ Vf,
    float* __restrict__ Cout)
{
  __shared__ u16 ldsA[16 * 512];       // 16 KiB (single buffer)
  __shared__ u16 ldsB[16 * 512];

  const int t  = threadIdx.x;
  const int l  = t & 63;
  const int w  = t >> 6;
  const int lr = l >> 4, lc = l & 15;

  const int nwg = gridDim.x;
  const int qq = nwg >> 3, rr8 = nwg & 7;
  const int xcd = blockIdx.x & 7, off = blockIdx.x >> 3;
  const int wgid = (xcd < rr8 ? xcd * (qq + 1) : rr8 * (qq + 1) + (xcd - rr8) * qq) + off;
  const int m0 = (wgid / nb) * 128;
  const int n0 = (wgid % nb) * 128;

  const u16* pA = Af + ((size_t)(m0 >> 7) * 128 + w) * 512 + l * 8;
  const u16* pB = Bf + ((size_t)(n0 >> 7) * 128 + w) * 512 + l * 8;

  f32x4 acc[4][4] = {};

  for (int kt = 0; kt < 8; ++kt) {
    __syncthreads();                   // prev compute done: buffer reusable
    const u16* qA = pA + kt * 8192;
    const u16* qB = pB + kt * 8192;
#pragma unroll
    for (int c = 0; c < 4; ++c) {
      async_copy16(&ldsA[(c * 4 + w) * 512], qA + c * 2048);
      async_copy16(&ldsB[(c * 4 + w) * 512], qB + c * 2048);
    }
    __syncthreads();                   // stage landed (vmcnt drain)
#pragma unroll
    for (int kk = 0; kk < 2; ++kk) {
      bf16x8 af[4], bfr[4];
#pragma unroll
      for (int m = 0; m < 4; ++m)
        af[m] = *(bf16x8*)&ldsA[((kk * 8 + (w >> 1) * 4 + m) * 64 + l) * 8];
#pragma unroll
      for (int n = 0; n < 4; ++n)
        bfr[n] = *(bf16x8*)&ldsB[((kk * 8 + (w & 1) * 4 + n) * 64 + l) * 8];
      __builtin_amdgcn_s_setprio(1);
#pragma unroll
      for (int m = 0; m < 4; ++m)
#pragma unroll
        for (int n = 0; n < 4; ++n)
          acc[m][n] = __builtin_amdgcn_mfma_f32_16x16x32_bf16(af[m], bfr[n], acc[m][n], 0, 0, 0);
      __builtin_amdgcn_s_setprio(0);
    }
  }

  int jv[4]; float bj[4];
#pragma unroll
  for (int n = 0; n < 4; ++n) { jv[n] = n0 + (w & 1) * 64 + n * 16 + lc; bj[n] = bias[jv[n]]; }

#pragma unroll
  for (int m = 0; m < 4; ++m) {
#pragma unroll
    for (int r = 0; r < 4; ++r) {
      int i = m0 + (w >> 1) * 64 + m * 16 + lr * 4 + r;
      if (i >= MTOK) continue;
      if (MODE == 0) {
        int b = i / S_, s = i - b * S_;
        int stK  = s >> 5;
        int nfs  = (s >> 4) & 1;
        int lisK = s & 15;
        int lvhi = (s >> 3) & 3;
        int es   = s & 7;
#pragma unroll
        for (int n = 0; n < 4; ++n) {
          int j = jv[n];
          int which = j >> 9, h = (j >> 8) & 1, d = j & 255;
          int bh = b * H_ + h;
          u16 v = f2bf(acc[m][n][r] + bj[n]);
          if (which == 0) {
            Qb[((size_t)(bh * SPAD + s)) * HD_ + d] = v;
          } else if (which == 1) {
            Kf[(((size_t)(bh * NKT + stK)) * 16 + (d >> 5) * 2 + nfs) * 512 +
               (((d >> 3) & 3) * 16 + lisK) * 8 + (d & 7)] = v;
          } else {
            Vf[(((size_t)(bh * NKT + stK)) * 16 + (d >> 4)) * 512 +
               (lvhi * 16 + (d & 15)) * 8 + es] = v;
          }
        }
      } else {
#pragma unroll
        for (int n = 0; n < 4; ++n)
          Cout[(size_t)i * D_ + jv[n]] = acc[m][n][r] + bj[n];
      }
    }
  }
}

// ---------------------------------------------------------------------------
// Kernel 3: causal flash attention v10 — BARRIER-FREE.
// Rounds 10-13 showed every variant keeping the per-iteration __syncthreads
// lands at 70-77 µs regardless of geometry: the barrier couples all waves to
// the slowest drain. The only cross-wave coupling was the K LDS dbuf — so K
// now loads DIRECT TO REGISTERS (same bytes as the LDS path: frag kb*2+nf,
// lane l = K[kv=nf*16+lc][d=kb*32+lr*8+e] = QK A-operand), time-sharing one
// kv[16] register block with V (K dead after QK^T). P stays in wave-private
// ldsP (same-wave lgkm ordering; no barrier needed — proven rounds 2-6).
// Zero barriers, 4.5 KB LDS -> waves fully independent (m114 TLP hiding).
// Cost: K re-read per wave (x4); K+V ~1.56 GB from L2 (XCD-pinned, ~4.3 TB/s
// per-XCD ceiling -> ~45 µs floor).
// ---------------------------------------------------------------------------
__global__ __launch_bounds__(256, 2) void attn_kernel(
    const u16* __restrict__ Qb, const u16* __restrict__ Kf,
    const u16* __restrict__ Vf, u16* __restrict__ Obf)
{
  __shared__ u16 ldsP[4][16 * 36];      // per-wave P [16 q][32 kv], pad 36

  const int id   = blockIdx.x;          // 0..607
  const int xcd  = id & 7;
  const int slot = id >> 3;             // 0..75
  const int bh   = xcd + 8 * (slot / 19);
  const int qt   = 18 - (slot % 19);    // long blocks first
  const int q0   = qt * 64;
  const int nkv  = 2 * qt + 2;          // kv tiles of 32
  const int t  = threadIdx.x, l = t & 63, w = t >> 6;
  const int lr = l >> 4, lc = l & 15;
  const int wq0 = q0 + w * 16;          // wave's first q row
  const int qrow_l = wq0 + lc;          // THIS lane's q row (swapped space)

  // Q fragments (B-operand rows=q over d): 8 d-blocks of 32
  bf16x8 qf[8];
  const u16* qbase = Qb + (size_t)(bh * SPAD + qrow_l) * HD_ + lr * 8;
#pragma unroll
  for (int kb = 0; kb < 8; ++kb)
    qf[kb] = *(const bf16x8*)(qbase + kb * 32);

  f32x4 oacc[16] = {};                  // [d-block]; col=q=lc, reg=d-sub
  float mrow = -1e30f, lsum = 0.f;      // per-lane scalars (q = lc)

  const u16* kroot = Kf + (((size_t)(bh * NKT)) * 16) * 512 + l * 8;
  const u16* vroot = Vf + (((size_t)(bh * NKT)) * 16) * 512 + l * 8;

  for (int kt = 0; kt < nkv; ++kt) {
    // (1) K-frag loads for this tile -> registers (time-shared with V)
    bf16x8 kv[16];
    {
      const u16* kb_ = kroot + (size_t)kt * 16 * 512;
#pragma unroll
      for (int f = 0; f < 16; ++f)
        kv[f] = *(const bf16x8*)(kb_ + f * 512);
    }

    // (2) S^T = K @ Q^T : A=kv (rows=kv), B=qf (rows=q) -> col=q, row=kv
    f32x4 sacc[2] = {};
    __builtin_amdgcn_s_setprio(1);
#pragma unroll
    for (int kb = 0; kb < 8; ++kb) {
#pragma unroll
      for (int nf = 0; nf < 2; ++nf)
        sacc[nf] = __builtin_amdgcn_mfma_f32_16x16x32_bf16(kv[kb * 2 + nf], qf[kb], sacc[nf], 0, 0, 0);
    }
    __builtin_amdgcn_s_setprio(0);

    // (3) V-frag loads (reuse kv regs; K is dead) — latency hidden under
    // softmax VALU + other waves (no barrier anywhere).
    {
      const u16* vb_ = vroot + (size_t)kt * 16 * 512;
#pragma unroll
      for (int f = 0; f < 16; ++f)
        kv[f] = *(const bf16x8*)(vb_ + f * 512);
    }

    // (4) mask + scale; per-lane row-max (lane = one q-row)
    const int kv0 = kt * 32;
    float sv[2][4];
    float pm = -1e30f;
    if (kv0 + 31 <= wq0) {              // interior
#pragma unroll
      for (int nf = 0; nf < 2; ++nf)
#pragma unroll
        for (int r = 0; r < 4; ++r) {
          float v = sacc[nf][r] * 0.0625f;
          sv[nf][r] = v;
          pm = fmaxf(pm, v);
        }
    } else {
#pragma unroll
      for (int nf = 0; nf < 2; ++nf)
#pragma unroll
        for (int r = 0; r < 4; ++r) {
          int kvi = kv0 + nf * 16 + lr * 4 + r;
          float v = ((kvi <= qrow_l) && (kvi < S_)) ? sacc[nf][r] * 0.0625f : -1e30f;
          sv[nf][r] = v;
          pm = fmaxf(pm, v);
        }
    }
    pm = fmaxf(pm, __shfl_xor(pm, 16));
    pm = fmaxf(pm, __shfl_xor(pm, 32));

    // defer-max (T13)
    bool skip = (pm <= mrow + 8.0f);
    if (!__all(skip)) {
      float mn = fmaxf(mrow, pm);
      float sc = exp2f((mrow - mn) * LOG2E);
      mrow = mn;
      lsum *= sc;
#pragma unroll
      for (int nf = 0; nf < 16; ++nf)
#pragma unroll
        for (int r = 0; r < 4; ++r) oacc[nf][r] *= sc;
    }

    // exp + P-write (packed b64; wave-private, same-wave lgkm ordering)
#pragma unroll
    for (int nf = 0; nf < 2; ++nf) {
      float p0 = exp2f((sv[nf][0] - mrow) * LOG2E);
      float p1 = exp2f((sv[nf][1] - mrow) * LOG2E);
      float p2 = exp2f((sv[nf][2] - mrow) * LOG2E);
      float p3 = exp2f((sv[nf][3] - mrow) * LOG2E);
      lsum += (p0 + p1) + (p2 + p3);
      uint64_t pk = (uint64_t)f2bf(p0) | ((uint64_t)f2bf(p1) << 16) |
                    ((uint64_t)f2bf(p2) << 32) | ((uint64_t)f2bf(p3) << 48);
      *(uint64_t*)&ldsP[w][lc * 36 + nf * 16 + lr * 4] = pk;
    }

    // (5) O^T += V^T @ P^T : A=kv (=V, rows=d), B=pf (rows=q) -> col=q, row=d
    bf16x8 pf = *(bf16x8*)&ldsP[w][lc * 36 + lr * 8];
    __builtin_amdgcn_s_setprio(1);
#pragma unroll
    for (int nf = 0; nf < 16; ++nf)
      oacc[nf] = __builtin_amdgcn_mfma_f32_16x16x32_bf16(kv[nf], pf, oacc[nf], 0, 0, 0);
    __builtin_amdgcn_s_setprio(0);
  }

  // finalize
  float s = lsum;
  s += __shfl_xor(s, 16);
  s += __shfl_xor(s, 32);
  float inv = 1.0f / s;

  const int b = bh >> 1, h = bh & 1;
  if (qrow_l < S_) {
    int i = b * S_ + qrow_l;
    int it = i >> 7, mf = (i >> 4) & 7, li = i & 15;
#pragma unroll
    for (int nf = 0; nf < 16; ++nf) {
#pragma unroll
      for (int r = 0; r < 4; ++r) {
        int j = h * HD_ + nf * 16 + lr * 4 + r;
        size_t addr = (((size_t)(it * 8 + (j >> 6))) * 16 + ((j >> 5) & 1) * 8 + mf) * 512 +
                      (((j >> 3) & 3) * 16 + li) * 8 + (j & 7);
        Obf[addr] = f2bf(oacc[nf][r] * inv);
      }
    }
  }
}

// ---------------------------------------------------------------------------
extern "C" void kernel_launch(void* const* d_in, const int* in_sizes, int n_in,
                              void* d_out, int out_size, void* d_ws, size_t ws_size,
                              hipStream_t stream) {
  const float* X    = (const float*)d_in[0];
  const float* Wqkv = (const float*)d_in[1];
  const float* bqkv = (const float*)d_in[2];
  const float* Wout = (const float*)d_in[3];
  const float* bout = (const float*)d_in[4];
  float* out = (float*)d_out;

  char* ws = (char*)d_ws;
  u16* Xf  = (u16*)ws;  ws += (size_t)MPAD * D_ * 2;
  u16* Wqf = (u16*)ws;  ws += (size_t)NQKV * D_ * 2;
  u16* Wof = (u16*)ws;  ws += (size_t)D_ * D_ * 2;
  u16* Qb  = (u16*)ws;  ws += (size_t)B_ * H_ * SPAD * HD_ * 2;
  u16* Kf  = (u16*)ws;  ws += (size_t)B_ * H_ * SPAD * HD_ * 2;
  u16* Vf  = (u16*)ws;  ws += (size_t)B_ * H_ * SPAD * HD_ * 2;
  u16* Obf = (u16*)ws;  ws += (size_t)MPAD * D_ * 2;
  // total ~101 MB

  convert_kernel<<<2048, 256, 0, stream>>>(X, Wqkv, Wout, Xf, Wqf, Wof);
  gemm_kernel<0><<<1800, 256, 0, stream>>>(Xf, Wqf, bqkv, 12, Qb, Kf, Vf, nullptr);
  attn_kernel<<<608, 256, 0, stream>>>(Qb, Kf, Vf, Obf);
  gemm_kernel<1><<<600, 256, 0, stream>>>(Obf, Wof, bout, 4, nullptr, nullptr, nullptr, out);
}

// Round 15
// 152.072 us; speedup vs baseline: 1.0510x; 1.0510x over previous
//
#include <hip/hip_runtime.h>
#include <stdint.h>

#define D_    512
#define H_    2
#define HD_   256
#define B_    16
#define S_    1194
#define MTOK  19104          // B_*S_
#define MPAD  19200          // 150*128
#define SPAD  1216           // 19*64 = 38*32
#define NQKV  1536
#define NKT   38             // kv tiles of 32 (global layout granularity)
#define LOG2E 1.44269504088896340736f

typedef unsigned short u16;
typedef __attribute__((ext_vector_type(8))) short bf16x8;   // 8 bf16 = 4 VGPR
typedef __attribute__((ext_vector_type(4))) float f32x4;

__device__ inline u16 f2bf(float x) {
  union { float f; unsigned u; } c; c.f = x;
  unsigned r = c.u + 0x7fffu + ((c.u >> 16) & 1u);  // RNE
  return (u16)(r >> 16);
}

// async global->LDS, 16B per lane. LDS dest is wave-uniform base (HW adds
// lane*16); global src per-lane, CONTIGUOUS: 1 instr = 1KB sequential.
__device__ inline void async_copy16(void* lds, const void* g) {
  __builtin_amdgcn_global_load_lds(
      (__attribute__((address_space(1))) void*)(g),
      (__attribute__((address_space(3))) void*)(lds),
      16, 0, 0);
}

// ---------------------------------------------------------------------------
// Kernel 1 (unchanged): X/W -> frag-major bf16.
// ---------------------------------------------------------------------------
__global__ void convert_kernel(const float* __restrict__ X,
                               const float* __restrict__ Wqkv,
                               const float* __restrict__ Wout,
                               u16* __restrict__ Xf,
                               u16* __restrict__ Wqf,
                               u16* __restrict__ Wof) {
  const int NXG = MPAD * 64;
  const int NQG = 12 * 8 * 16 * 64;
  const int NOG = 4 * 8 * 16 * 64;
  const int TOT = NXG + NQG + NOG;
  int stride = gridDim.x * blockDim.x;
  for (int g = blockIdx.x * blockDim.x + threadIdx.x; g < TOT; g += stride) {
    if (g < NXG) {
      int lane = g & 63, f = (g >> 6) & 15, kt = (g >> 10) & 7, mt = g >> 13;
      int i = mt * 128 + (f & 7) * 16 + (lane & 15);
      int k = kt * 64 + (f >> 3) * 32 + (lane >> 4) * 8;
      bf16x8 o;
      if (i < MTOK) {
        f32x4 v0 = *(const f32x4*)&X[(size_t)i * 512 + k];
        f32x4 v1 = *(const f32x4*)&X[(size_t)i * 512 + k + 4];
#pragma unroll
        for (int e = 0; e < 4; ++e) { o[e] = (short)f2bf(v0[e]); o[4 + e] = (short)f2bf(v1[e]); }
      } else {
#pragma unroll
        for (int e = 0; e < 8; ++e) o[e] = 0;
      }
      *(bf16x8*)&Xf[(size_t)g * 8] = o;
    } else if (g < NXG + NQG) {
      int gg = g - NXG;
      int lane = gg & 63, f = (gg >> 6) & 15, kt = (gg >> 10) & 7, nt = gg >> 13;
      int j = nt * 128 + (f & 7) * 16 + (lane & 15);
      int k = kt * 64 + (f >> 3) * 32 + (lane >> 4) * 8;
      bf16x8 o;
#pragma unroll
      for (int e = 0; e < 8; ++e) o[e] = (short)f2bf(Wqkv[(size_t)(k + e) * NQKV + j]);
      *(bf16x8*)&Wqf[(size_t)gg * 8] = o;
    } else {
      int gg = g - NXG - NQG;
      int lane = gg & 63, f = (gg >> 6) & 15, kt = (gg >> 10) & 7, nt = gg >> 13;
      int j = nt * 128 + (f & 7) * 16 + (lane & 15);
      int k = kt * 64 + (f >> 3) * 32 + (lane >> 4) * 8;
      bf16x8 o;
#pragma unroll
      for (int e = 0; e < 8; ++e) o[e] = (short)f2bf(Wout[(size_t)(k + e) * 512 + j]);
      *(bf16x8*)&Wof[(size_t)gg * 8] = o;
    }
  }
}

// ---------------------------------------------------------------------------
// GEMM v2 (unchanged from round 10): m97 single-buffer schedule.
// ---------------------------------------------------------------------------
template<int MODE>
__global__ __launch_bounds__(256, 2) void gemm_kernel(
    const u16* __restrict__ Af, const u16* __restrict__ Bf,
    const float* __restrict__ bias, int nb,
    u16* __restrict__ Qb, u16* __restrict__ Kf, u16* __restrict__ Vf,
    float* __restrict__ Cout)
{
  __shared__ u16 ldsA[16 * 512];       // 16 KiB (single buffer)
  __shared__ u16 ldsB[16 * 512];

  const int t  = threadIdx.x;
  const int l  = t & 63;
  const int w  = t >> 6;
  const int lr = l >> 4, lc = l & 15;

  const int nwg = gridDim.x;
  const int qq = nwg >> 3, rr8 = nwg & 7;
  const int xcd = blockIdx.x & 7, off = blockIdx.x >> 3;
  const int wgid = (xcd < rr8 ? xcd * (qq + 1) : rr8 * (qq + 1) + (xcd - rr8) * qq) + off;
  const int m0 = (wgid / nb) * 128;
  const int n0 = (wgid % nb) * 128;

  const u16* pA = Af + ((size_t)(m0 >> 7) * 128 + w) * 512 + l * 8;
  const u16* pB = Bf + ((size_t)(n0 >> 7) * 128 + w) * 512 + l * 8;

  f32x4 acc[4][4] = {};

  for (int kt = 0; kt < 8; ++kt) {
    __syncthreads();                   // prev compute done: buffer reusable
    const u16* qA = pA + kt * 8192;
    const u16* qB = pB + kt * 8192;
#pragma unroll
    for (int c = 0; c < 4; ++c) {
      async_copy16(&ldsA[(c * 4 + w) * 512], qA + c * 2048);
      async_copy16(&ldsB[(c * 4 + w) * 512], qB + c * 2048);
    }
    __syncthreads();                   // stage landed (vmcnt drain)
#pragma unroll
    for (int kk = 0; kk < 2; ++kk) {
      bf16x8 af[4], bfr[4];
#pragma unroll
      for (int m = 0; m < 4; ++m)
        af[m] = *(bf16x8*)&ldsA[((kk * 8 + (w >> 1) * 4 + m) * 64 + l) * 8];
#pragma unroll
      for (int n = 0; n < 4; ++n)
        bfr[n] = *(bf16x8*)&ldsB[((kk * 8 + (w & 1) * 4 + n) * 64 + l) * 8];
      __builtin_amdgcn_s_setprio(1);
#pragma unroll
      for (int m = 0; m < 4; ++m)
#pragma unroll
        for (int n = 0; n < 4; ++n)
          acc[m][n] = __builtin_amdgcn_mfma_f32_16x16x32_bf16(af[m], bfr[n], acc[m][n], 0, 0, 0);
      __builtin_amdgcn_s_setprio(0);
    }
  }

  int jv[4]; float bj[4];
#pragma unroll
  for (int n = 0; n < 4; ++n) { jv[n] = n0 + (w & 1) * 64 + n * 16 + lc; bj[n] = bias[jv[n]]; }

#pragma unroll
  for (int m = 0; m < 4; ++m) {
#pragma unroll
    for (int r = 0; r < 4; ++r) {
      int i = m0 + (w >> 1) * 64 + m * 16 + lr * 4 + r;
      if (i >= MTOK) continue;
      if (MODE == 0) {
        int b = i / S_, s = i - b * S_;
        int stK  = s >> 5;
        int nfs  = (s >> 4) & 1;
        int lisK = s & 15;
        int lvhi = (s >> 3) & 3;
        int es   = s & 7;
#pragma unroll
        for (int n = 0; n < 4; ++n) {
          int j = jv[n];
          int which = j >> 9, h = (j >> 8) & 1, d = j & 255;
          int bh = b * H_ + h;
          u16 v = f2bf(acc[m][n][r] + bj[n]);
          if (which == 0) {
            Qb[((size_t)(bh * SPAD + s)) * HD_ + d] = v;
          } else if (which == 1) {
            Kf[(((size_t)(bh * NKT + stK)) * 16 + (d >> 5) * 2 + nfs) * 512 +
               (((d >> 3) & 3) * 16 + lisK) * 8 + (d & 7)] = v;
          } else {
            Vf[(((size_t)(bh * NKT + stK)) * 16 + (d >> 4)) * 512 +
               (lvhi * 16 + (d & 15)) * 8 + es] = v;
          }
        }
      } else {
#pragma unroll
        for (int n = 0; n < 4; ++n)
          Cout[(size_t)i * D_ + jv[n]] = acc[m][n][r] + bj[n];
      }
    }
  }
}

// ---------------------------------------------------------------------------
// Kernel 3: causal flash attention v11 = round-10 v6 + CROSS-TILE PIPELINE:
// in iteration j, softmax(j) and QK(j+1) share one barrier-free region, so
// the next tile's MFMAs hide this tile's softmax VALU/bpermute/LDS latency
// (intra-wave dual-pipe overlap). sacc ping-pongs between NAMED arrays
// saccA/saccB (nkv always even -> unroll-by-2, rule #20 safe).
// Buffer safety: K(j) in buf[j&1]; stage K(j+2)->buf[j&1] happens one barrier
// after all waves' QK(j); extra prologue barrier protects buf0's first reuse.
// Everything else (masking, defer-max, P path, PV, output) = v6 verbatim.
// ---------------------------------------------------------------------------
__global__ __launch_bounds__(256, 2) void attn_kernel(
    const u16* __restrict__ Qb, const u16* __restrict__ Kf,
    const u16* __restrict__ Vf, u16* __restrict__ Obf)
{
  __shared__ u16 ldsK[2][16 * 512];     // 2 x 16 KiB, frag = kb*2+nf
  __shared__ u16 ldsP[4][16 * 36];      // per-wave P [16 q][32 kv], pad 36

  const int id   = blockIdx.x;          // 0..607
  const int xcd  = id & 7;
  const int slot = id >> 3;             // 0..75
  const int bh   = xcd + 8 * (slot / 19);
  const int qt   = 18 - (slot % 19);    // long blocks first
  const int q0   = qt * 64;
  const int nkv  = 2 * qt + 2;          // kv tiles of 32 (ALWAYS EVEN)
  const int t  = threadIdx.x, l = t & 63, w = t >> 6;
  const int lr = l >> 4, lc = l & 15;
  const int wq0 = q0 + w * 16;          // wave's first q row
  const int qrow_l = wq0 + lc;          // THIS lane's q row (swapped space)

  // Q fragments (B-operand rows=q over d): 8 d-blocks of 32
  bf16x8 qf[8];
  const u16* qbase = Qb + (size_t)(bh * SPAD + qrow_l) * HD_ + lr * 8;
#pragma unroll
  for (int kb = 0; kb < 8; ++kb)
    qf[kb] = *(const bf16x8*)(qbase + kb * 32);

  f32x4 oacc[16] = {};                  // [d-block]; col=q=lc, reg=d-sub
  float mrow = -1e30f, lsum = 0.f;      // per-lane scalars (q = lc)

  const u16* kroot = Kf + ((size_t)(bh * NKT) * 16 + w) * 512 + l * 8;
  const u16* vroot = Vf + ((size_t)(bh * NKT) * 16) * 512 + l * 8;

  // prologue: stage K(0)->buf0, K(1)->buf1 (nkv >= 2 always)
#pragma unroll
  for (int c = 0; c < 4; ++c) {
    async_copy16(&ldsK[0][(c * 4 + w) * 512], kroot + c * 2048);
    async_copy16(&ldsK[1][(c * 4 + w) * 512], kroot + 8192 + c * 2048);
  }
  __syncthreads();

  f32x4 saccA[2] = {}, saccB[2] = {};
  // QK(0) -> saccA
  __builtin_amdgcn_s_setprio(1);
#pragma unroll
  for (int kb = 0; kb < 8; ++kb)
#pragma unroll
    for (int nf = 0; nf < 2; ++nf) {
      bf16x8 kf = *(bf16x8*)&ldsK[0][((kb * 2 + nf) * 64 + l) * 8];
      saccA[nf] = __builtin_amdgcn_mfma_f32_16x16x32_bf16(kf, qf[kb], saccA[nf], 0, 0, 0);
    }
  __builtin_amdgcn_s_setprio(0);
  __syncthreads();   // all waves past QK(0) before buf0 is restaged in sub-iter 0

  // SUBITER(j, S, N): V(j) loads; stage K(j+2)->buf[j&1]; softmax(j) on S;
  // QK(j+1)->N (if exists); barrier; PV(j).
#define SUBITER(J, S, N)                                                       \
  {                                                                            \
    const int j_ = (J);                                                        \
    bf16x8 vfr[16];                                                            \
    {                                                                          \
      const u16* vb_ = vroot + (size_t)j_ * 8192;                              \
      _Pragma("unroll")                                                        \
      for (int f = 0; f < 16; ++f) vfr[f] = *(const bf16x8*)(vb_ + f * 512);   \
    }                                                                          \
    if (j_ + 2 < nkv) {                                                        \
      const u16* kb_ = kroot + (size_t)(j_ + 2) * 8192;                        \
      _Pragma("unroll")                                                        \
      for (int c = 0; c < 4; ++c)                                              \
        async_copy16(&ldsK[j_ & 1][(c * 4 + w) * 512], kb_ + c * 2048);        \
    }                                                                          \
    const int kv0 = j_ * 32;                                                   \
    float sv[2][4];                                                            \
    float pm = -1e30f;                                                         \
    if (kv0 + 31 <= wq0) {                                                     \
      _Pragma("unroll")                                                        \
      for (int nf = 0; nf < 2; ++nf)                                           \
        _Pragma("unroll")                                                      \
        for (int r = 0; r < 4; ++r) {                                          \
          float v = S[nf][r] * 0.0625f;                                        \
          sv[nf][r] = v;                                                       \
          pm = fmaxf(pm, v);                                                   \
        }                                                                      \
    } else {                                                                   \
      _Pragma("unroll")                                                        \
      for (int nf = 0; nf < 2; ++nf)                                           \
        _Pragma("unroll")                                                      \
        for (int r = 0; r < 4; ++r) {                                          \
          int kvi = kv0 + nf * 16 + lr * 4 + r;                                \
          float v = ((kvi <= qrow_l) && (kvi < S_)) ? S[nf][r] * 0.0625f       \
                                                    : -1e30f;                  \
          sv[nf][r] = v;                                                       \
          pm = fmaxf(pm, v);                                                   \
        }                                                                      \
    }                                                                          \
    pm = fmaxf(pm, __shfl_xor(pm, 16));                                        \
    pm = fmaxf(pm, __shfl_xor(pm, 32));                                        \
    bool skip = (pm <= mrow + 8.0f);                                           \
    if (!__all(skip)) {                                                        \
      float mn = fmaxf(mrow, pm);                                              \
      float sc = exp2f((mrow - mn) * LOG2E);                                   \
      mrow = mn;                                                               \
      lsum *= sc;                                                              \
      _Pragma("unroll")                                                        \
      for (int nf = 0; nf < 16; ++nf)                                          \
        _Pragma("unroll")                                                      \
        for (int r = 0; r < 4; ++r) oacc[nf][r] *= sc;                         \
    }                                                                          \
    _Pragma("unroll")                                                          \
    for (int nf = 0; nf < 2; ++nf) {                                           \
      float p0 = exp2f((sv[nf][0] - mrow) * LOG2E);                            \
      float p1 = exp2f((sv[nf][1] - mrow) * LOG2E);                            \
      float p2 = exp2f((sv[nf][2] - mrow) * LOG2E);                            \
      float p3 = exp2f((sv[nf][3] - mrow) * LOG2E);                            \
      lsum += (p0 + p1) + (p2 + p3);                                           \
      uint64_t pk = (uint64_t)f2bf(p0) | ((uint64_t)f2bf(p1) << 16) |          \
                    ((uint64_t)f2bf(p2) << 32) | ((uint64_t)f2bf(p3) << 48);   \
      *(uint64_t*)&ldsP[w][lc * 36 + nf * 16 + lr * 4] = pk;                   \
    }                                                                          \
    if (j_ + 1 < nkv) {                                                        \
      N[0] = (f32x4){0.f, 0.f, 0.f, 0.f};                                      \
      N[1] = (f32x4){0.f, 0.f, 0.f, 0.f};                                      \
      __builtin_amdgcn_s_setprio(1);                                           \
      _Pragma("unroll")                                                        \
      for (int kb = 0; kb < 8; ++kb)                                           \
        _Pragma("unroll")                                                      \
        for (int nf = 0; nf < 2; ++nf) {                                       \
          bf16x8 kf =                                                          \
              *(bf16x8*)&ldsK[(j_ + 1) & 1][((kb * 2 + nf) * 64 + l) * 8];     \
          N[nf] = __builtin_amdgcn_mfma_f32_16x16x32_bf16(kf, qf[kb], N[nf],   \
                                                          0, 0, 0);            \
        }                                                                      \
      __builtin_amdgcn_s_setprio(0);                                           \
    }                                                                          \
    __syncthreads();                                                           \
    bf16x8 pf = *(bf16x8*)&ldsP[w][lc * 36 + lr * 8];                          \
    __builtin_amdgcn_s_setprio(1);                                             \
    _Pragma("unroll")                                                          \
    for (int nf = 0; nf < 16; ++nf)                                            \
      oacc[nf] =                                                               \
          __builtin_amdgcn_mfma_f32_16x16x32_bf16(vfr[nf], pf, oacc[nf],       \
                                                  0, 0, 0);                    \
    __builtin_amdgcn_s_setprio(0);                                             \
  }

  for (int kt = 0; kt < nkv; kt += 2) {
    SUBITER(kt, saccA, saccB);        // softmax(kt); QK(kt+1)->saccB (always)
    SUBITER(kt + 1, saccB, saccA);    // softmax(kt+1); QK(kt+2)->saccA if any
  }
#undef SUBITER

  // finalize
  float s = lsum;
  s += __shfl_xor(s, 16);
  s += __shfl_xor(s, 32);
  float inv = 1.0f / s;

  const int b = bh >> 1, h = bh & 1;
  if (qrow_l < S_) {
    int i = b * S_ + qrow_l;
    int it = i >> 7, mf = (i >> 4) & 7, li = i & 15;
#pragma unroll
    for (int nf = 0; nf < 16; ++nf) {
#pragma unroll
      for (int r = 0; r < 4; ++r) {
        int j = h * HD_ + nf * 16 + lr * 4 + r;
        size_t addr = (((size_t)(it * 8 + (j >> 6))) * 16 + ((j >> 5) & 1) * 8 + mf) * 512 +
                      (((j >> 3) & 3) * 16 + li) * 8 + (j & 7);
        Obf[addr] = f2bf(oacc[nf][r] * inv);
      }
    }
  }
}

// ---------------------------------------------------------------------------
extern "C" void kernel_launch(void* const* d_in, const int* in_sizes, int n_in,
                              void* d_out, int out_size, void* d_ws, size_t ws_size,
                              hipStream_t stream) {
  const float* X    = (const float*)d_in[0];
  const float* Wqkv = (const float*)d_in[1];
  const float* bqkv = (const float*)d_in[2];
  const float* Wout = (const float*)d_in[3];
  const float* bout = (const float*)d_in[4];
  float* out = (float*)d_out;

  char* ws = (char*)d_ws;
  u16* Xf  = (u16*)ws;  ws += (size_t)MPAD * D_ * 2;
  u16* Wqf = (u16*)ws;  ws += (size_t)NQKV * D_ * 2;
  u16* Wof = (u16*)ws;  ws += (size_t)D_ * D_ * 2;
  u16* Qb  = (u16*)ws;  ws += (size_t)B_ * H_ * SPAD * HD_ * 2;
  u16* Kf  = (u16*)ws;  ws += (size_t)B_ * H_ * SPAD * HD_ * 2;
  u16* Vf  = (u16*)ws;  ws += (size_t)B_ * H_ * SPAD * HD_ * 2;
  u16* Obf = (u16*)ws;  ws += (size_t)MPAD * D_ * 2;
  // total ~101 MB

  convert_kernel<<<2048, 256, 0, stream>>>(X, Wqkv, Wout, Xf, Wqf, Wof);
  gemm_kernel<0><<<1800, 256, 0, stream>>>(Xf, Wqf, bqkv, 12, Qb, Kf, Vf, nullptr);
  attn_kernel<<<608, 256, 0, stream>>>(Qb, Kf, Vf, Obf);
  gemm_kernel<1><<<600, 256, 0, stream>>>(Obf, Wof, bout, 4, nullptr, nullptr, nullptr, out);
}

// Round 16
// 147.892 us; speedup vs baseline: 1.0807x; 1.0283x over previous
//
#include <hip/hip_runtime.h>
#include <stdint.h>

#define D_    512
#define H_    2
#define HD_   256
#define B_    16
#define S_    1194
#define MTOK  19104          // B_*S_  (even; batch boundaries at even i)
#define MPAD  19200          // 150*128
#define SPAD  1216           // 19*64 = 38*32
#define NQKV  1536
#define NKT   38             // kv tiles of 32 (global layout granularity)
#define LOG2E 1.44269504088896340736f

typedef unsigned short u16;
typedef unsigned int u32;
typedef __attribute__((ext_vector_type(8))) short bf16x8;   // 8 bf16 = 4 VGPR
typedef __attribute__((ext_vector_type(4))) float f32x4;

__device__ inline u16 f2bf(float x) {
  union { float f; unsigned u; } c; c.f = x;
  unsigned r = c.u + 0x7fffu + ((c.u >> 16) & 1u);  // RNE
  return (u16)(r >> 16);
}

// async global->LDS, 16B per lane. LDS dest is wave-uniform base (HW adds
// lane*16); global src per-lane, CONTIGUOUS: 1 instr = 1KB sequential.
__device__ inline void async_copy16(void* lds, const void* g) {
  __builtin_amdgcn_global_load_lds(
      (__attribute__((address_space(1))) void*)(g),
      (__attribute__((address_space(3))) void*)(lds),
      16, 0, 0);
}

// ---------------------------------------------------------------------------
// Kernel 1 (unchanged): X/W -> frag-major bf16.
// ---------------------------------------------------------------------------
__global__ void convert_kernel(const float* __restrict__ X,
                               const float* __restrict__ Wqkv,
                               const float* __restrict__ Wout,
                               u16* __restrict__ Xf,
                               u16* __restrict__ Wqf,
                               u16* __restrict__ Wof) {
  const int NXG = MPAD * 64;
  const int NQG = 12 * 8 * 16 * 64;
  const int NOG = 4 * 8 * 16 * 64;
  const int TOT = NXG + NQG + NOG;
  int stride = gridDim.x * blockDim.x;
  for (int g = blockIdx.x * blockDim.x + threadIdx.x; g < TOT; g += stride) {
    if (g < NXG) {
      int lane = g & 63, f = (g >> 6) & 15, kt = (g >> 10) & 7, mt = g >> 13;
      int i = mt * 128 + (f & 7) * 16 + (lane & 15);
      int k = kt * 64 + (f >> 3) * 32 + (lane >> 4) * 8;
      bf16x8 o;
      if (i < MTOK) {
        f32x4 v0 = *(const f32x4*)&X[(size_t)i * 512 + k];
        f32x4 v1 = *(const f32x4*)&X[(size_t)i * 512 + k + 4];
#pragma unroll
        for (int e = 0; e < 4; ++e) { o[e] = (short)f2bf(v0[e]); o[4 + e] = (short)f2bf(v1[e]); }
      } else {
#pragma unroll
        for (int e = 0; e < 8; ++e) o[e] = 0;
      }
      *(bf16x8*)&Xf[(size_t)g * 8] = o;
    } else if (g < NXG + NQG) {
      int gg = g - NXG;
      int lane = gg & 63, f = (gg >> 6) & 15, kt = (gg >> 10) & 7, nt = gg >> 13;
      int j = nt * 128 + (f & 7) * 16 + (lane & 15);
      int k = kt * 64 + (f >> 3) * 32 + (lane >> 4) * 8;
      bf16x8 o;
#pragma unroll
      for (int e = 0; e < 8; ++e) o[e] = (short)f2bf(Wqkv[(size_t)(k + e) * NQKV + j]);
      *(bf16x8*)&Wqf[(size_t)gg * 8] = o;
    } else {
      int gg = g - NXG - NQG;
      int lane = gg & 63, f = (gg >> 6) & 15, kt = (gg >> 10) & 7, nt = gg >> 13;
      int j = nt * 128 + (f & 7) * 16 + (lane & 15);
      int k = kt * 64 + (f >> 3) * 32 + (lane >> 4) * 8;
      bf16x8 o;
#pragma unroll
      for (int e = 0; e < 8; ++e) o[e] = (short)f2bf(Wout[(size_t)(k + e) * 512 + j]);
      *(bf16x8*)&Wof[(size_t)gg * 8] = o;
    }
  }
}

// ---------------------------------------------------------------------------
// GEMM v3: m97 single-buffer schedule + VECTORIZED EPILOGUE.
// Each 128-col N-band of MODE 0 is purely Q, K, or V (bands 0-3/4-7/8-11).
// Q/K bands & MODE 1: SWAPPED operands mfma(bfr, af) -> D^T: lane holds fixed
// token i=..+lc and 4 CONSECUTIVE j per reg group -> 16 x 8B (u64) or f32x4
// stores + f32x4 bias loads (was 64 scattered scalars).
// V bands: original orientation; s consecutive over r (s even-aligned, pairs
// never straddle batch boundaries) -> 32 x 4B paired stores.
// ---------------------------------------------------------------------------
template<int MODE>
__global__ __launch_bounds__(256, 2) void gemm_kernel(
    const u16* __restrict__ Af, const u16* __restrict__ Bf,
    const float* __restrict__ bias, int nb,
    u16* __restrict__ Qb, u16* __restrict__ Kf, u16* __restrict__ Vf,
    float* __restrict__ Cout)
{
  __shared__ u16 ldsA[16 * 512];       // 16 KiB (single buffer)
  __shared__ u16 ldsB[16 * 512];

  const int t  = threadIdx.x;
  const int l  = t & 63;
  const int w  = t >> 6;
  const int lr = l >> 4, lc = l & 15;

  const int nwg = gridDim.x;
  const int qq = nwg >> 3, rr8 = nwg & 7;
  const int xcd = blockIdx.x & 7, off = blockIdx.x >> 3;
  const int wgid = (xcd < rr8 ? xcd * (qq + 1) : rr8 * (qq + 1) + (xcd - rr8) * qq) + off;
  const int m0 = (wgid / nb) * 128;
  const int n0 = (wgid % nb) * 128;
  const bool vband = (MODE == 0) && ((wgid % nb) >= 8);

  const u16* pA = Af + ((size_t)(m0 >> 7) * 128 + w) * 512 + l * 8;
  const u16* pB = Bf + ((size_t)(n0 >> 7) * 128 + w) * 512 + l * 8;

  f32x4 acc[4][4] = {};

  for (int kt = 0; kt < 8; ++kt) {
    __syncthreads();                   // prev compute done: buffer reusable
    const u16* qA = pA + kt * 8192;
    const u16* qB = pB + kt * 8192;
#pragma unroll
    for (int c = 0; c < 4; ++c) {
      async_copy16(&ldsA[(c * 4 + w) * 512], qA + c * 2048);
      async_copy16(&ldsB[(c * 4 + w) * 512], qB + c * 2048);
    }
    __syncthreads();                   // stage landed (vmcnt drain)
#pragma unroll
    for (int kk = 0; kk < 2; ++kk) {
      bf16x8 af[4], bfr[4];
#pragma unroll
      for (int m = 0; m < 4; ++m)
        af[m] = *(bf16x8*)&ldsA[((kk * 8 + (w >> 1) * 4 + m) * 64 + l) * 8];
#pragma unroll
      for (int n = 0; n < 4; ++n)
        bfr[n] = *(bf16x8*)&ldsB[((kk * 8 + (w & 1) * 4 + n) * 64 + l) * 8];
      __builtin_amdgcn_s_setprio(1);
      if (!vband) {                    // swapped: D^T (lane = fixed token i)
#pragma unroll
        for (int m = 0; m < 4; ++m)
#pragma unroll
          for (int n = 0; n < 4; ++n)
            acc[m][n] = __builtin_amdgcn_mfma_f32_16x16x32_bf16(bfr[n], af[m], acc[m][n], 0, 0, 0);
      } else {                         // original: lane = fixed col j
#pragma unroll
        for (int m = 0; m < 4; ++m)
#pragma unroll
          for (int n = 0; n < 4; ++n)
            acc[m][n] = __builtin_amdgcn_mfma_f32_16x16x32_bf16(af[m], bfr[n], acc[m][n], 0, 0, 0);
      }
      __builtin_amdgcn_s_setprio(0);
    }
  }

  if (MODE == 1) {
    // swapped: acc[m][n][r] = C[i = m0+(w>>1)*64+m*16+lc][j = jb(n)+r]
#pragma unroll
    for (int m = 0; m < 4; ++m) {
      int i = m0 + (w >> 1) * 64 + m * 16 + lc;
      if (i >= MTOK) continue;
#pragma unroll
      for (int n = 0; n < 4; ++n) {
        int jb = n0 + (w & 1) * 64 + n * 16 + lr * 4;
        f32x4 bv = *(const f32x4*)&bias[jb];
        f32x4 o;
#pragma unroll
        for (int r = 0; r < 4; ++r) o[r] = acc[m][n][r] + bv[r];
        *(f32x4*)&Cout[(size_t)i * D_ + jb] = o;
      }
    }
  } else if (!vband) {
    // Q/K bands, swapped layout: 4 consecutive j per group -> u64 stores
#pragma unroll
    for (int m = 0; m < 4; ++m) {
      int i = m0 + (w >> 1) * 64 + m * 16 + lc;
      if (i >= MTOK) continue;
      int b = i / S_, s = i - b * S_;
      int stK = s >> 5, nfs = (s >> 4) & 1, lisK = s & 15;
#pragma unroll
      for (int n = 0; n < 4; ++n) {
        int jb = n0 + (w & 1) * 64 + n * 16 + lr * 4;
        f32x4 bv = *(const f32x4*)&bias[jb];
        uint64_t pk = 0;
#pragma unroll
        for (int r = 0; r < 4; ++r)
          pk |= (uint64_t)f2bf(acc[m][n][r] + bv[r]) << (16 * r);
        int which = jb >> 9, h = (jb >> 8) & 1, d = jb & 255;
        int bh = b * H_ + h;
        if (which == 0) {
          *(uint64_t*)&Qb[(size_t)(bh * SPAD + s) * HD_ + d] = pk;
        } else {
          *(uint64_t*)&Kf[(((size_t)(bh * NKT + stK)) * 16 + (d >> 5) * 2 + nfs) * 512 +
                          (((d >> 3) & 3) * 16 + lisK) * 8 + (d & 7)] = pk;
        }
      }
    }
  } else {
    // V band, original layout: s consecutive over r -> paired u32 stores
    int jv[4]; float bj[4];
#pragma unroll
    for (int n = 0; n < 4; ++n) { jv[n] = n0 + (w & 1) * 64 + n * 16 + lc; bj[n] = bias[jv[n]]; }
#pragma unroll
    for (int m = 0; m < 4; ++m) {
#pragma unroll
      for (int rp = 0; rp < 4; rp += 2) {
        int i0 = m0 + (w >> 1) * 64 + m * 16 + lr * 4 + rp;   // even
        if (i0 >= MTOK) continue;                             // i0+1 < MTOK too
        int b = i0 / S_, s = i0 - b * S_;                     // pair same batch
        int stK = s >> 5, lvhi = (s >> 3) & 3, es = s & 7;    // es even
#pragma unroll
        for (int n = 0; n < 4; ++n) {
          int j = jv[n];
          int h = (j >> 8) & 1, d = j & 255;
          int bh = b * H_ + h;
          u32 pk = (u32)f2bf(acc[m][n][rp] + bj[n]) |
                   ((u32)f2bf(acc[m][n][rp + 1] + bj[n]) << 16);
          *(u32*)&Vf[(((size_t)(bh * NKT + stK)) * 16 + (d >> 4)) * 512 +
                     (lvhi * 16 + (d & 15)) * 8 + es] = pk;
        }
      }
    }
  }
}

// ---------------------------------------------------------------------------
// Kernel 3: causal flash attention v11 (round-15 champion) + packed output.
// ---------------------------------------------------------------------------
__global__ __launch_bounds__(256, 2) void attn_kernel(
    const u16* __restrict__ Qb, const u16* __restrict__ Kf,
    const u16* __restrict__ Vf, u16* __restrict__ Obf)
{
  __shared__ u16 ldsK[2][16 * 512];     // 2 x 16 KiB, frag = kb*2+nf
  __shared__ u16 ldsP[4][16 * 36];      // per-wave P [16 q][32 kv], pad 36

  const int id   = blockIdx.x;          // 0..607
  const int xcd  = id & 7;
  const int slot = id >> 3;             // 0..75
  const int bh   = xcd + 8 * (slot / 19);
  const int qt   = 18 - (slot % 19);    // long blocks first
  const int q0   = qt * 64;
  const int nkv  = 2 * qt + 2;          // kv tiles of 32 (ALWAYS EVEN)
  const int t  = threadIdx.x, l = t & 63, w = t >> 6;
  const int lr = l >> 4, lc = l & 15;
  const int wq0 = q0 + w * 16;          // wave's first q row
  const int qrow_l = wq0 + lc;          // THIS lane's q row (swapped space)

  // Q fragments (B-operand rows=q over d): 8 d-blocks of 32
  bf16x8 qf[8];
  const u16* qbase = Qb + (size_t)(bh * SPAD + qrow_l) * HD_ + lr * 8;
#pragma unroll
  for (int kb = 0; kb < 8; ++kb)
    qf[kb] = *(const bf16x8*)(qbase + kb * 32);

  f32x4 oacc[16] = {};                  // [d-block]; col=q=lc, reg=d-sub
  float mrow = -1e30f, lsum = 0.f;      // per-lane scalars (q = lc)

  const u16* kroot = Kf + ((size_t)(bh * NKT) * 16 + w) * 512 + l * 8;
  const u16* vroot = Vf + ((size_t)(bh * NKT) * 16) * 512 + l * 8;

  // prologue: stage K(0)->buf0, K(1)->buf1 (nkv >= 2 always)
#pragma unroll
  for (int c = 0; c < 4; ++c) {
    async_copy16(&ldsK[0][(c * 4 + w) * 512], kroot + c * 2048);
    async_copy16(&ldsK[1][(c * 4 + w) * 512], kroot + 8192 + c * 2048);
  }
  __syncthreads();

  f32x4 saccA[2] = {}, saccB[2] = {};
  // QK(0) -> saccA
  __builtin_amdgcn_s_setprio(1);
#pragma unroll
  for (int kb = 0; kb < 8; ++kb)
#pragma unroll
    for (int nf = 0; nf < 2; ++nf) {
      bf16x8 kf = *(bf16x8*)&ldsK[0][((kb * 2 + nf) * 64 + l) * 8];
      saccA[nf] = __builtin_amdgcn_mfma_f32_16x16x32_bf16(kf, qf[kb], saccA[nf], 0, 0, 0);
    }
  __builtin_amdgcn_s_setprio(0);
  __syncthreads();   // all waves past QK(0) before buf0 is restaged in sub-iter 0

  // SUBITER(j, S, N): V(j) loads; stage K(j+2)->buf[j&1]; softmax(j) on S;
  // QK(j+1)->N (if exists); barrier; PV(j).
#define SUBITER(J, S, N)                                                       \
  {                                                                            \
    const int j_ = (J);                                                        \
    bf16x8 vfr[16];                                                            \
    {                                                                          \
      const u16* vb_ = vroot + (size_t)j_ * 8192;                              \
      _Pragma("unroll")                                                        \
      for (int f = 0; f < 16; ++f) vfr[f] = *(const bf16x8*)(vb_ + f * 512);   \
    }                                                                          \
    if (j_ + 2 < nkv) {                                                        \
      const u16* kb_ = kroot + (size_t)(j_ + 2) * 8192;                        \
      _Pragma("unroll")                                                        \
      for (int c = 0; c < 4; ++c)                                              \
        async_copy16(&ldsK[j_ & 1][(c * 4 + w) * 512], kb_ + c * 2048);        \
    }                                                                          \
    const int kv0 = j_ * 32;                                                   \
    float sv[2][4];                                                            \
    float pm = -1e30f;                                                         \
    if (kv0 + 31 <= wq0) {                                                     \
      _Pragma("unroll")                                                        \
      for (int nf = 0; nf < 2; ++nf)                                           \
        _Pragma("unroll")                                                      \
        for (int r = 0; r < 4; ++r) {                                          \
          float v = S[nf][r] * 0.0625f;                                        \
          sv[nf][r] = v;                                                       \
          pm = fmaxf(pm, v);                                                   \
        }                                                                      \
    } else {                                                                   \
      _Pragma("unroll")                                                        \
      for (int nf = 0; nf < 2; ++nf)                                           \
        _Pragma("unroll")                                                      \
        for (int r = 0; r < 4; ++r) {                                          \
          int kvi = kv0 + nf * 16 + lr * 4 + r;                                \
          float v = ((kvi <= qrow_l) && (kvi < S_)) ? S[nf][r] * 0.0625f       \
                                                    : -1e30f;                  \
          sv[nf][r] = v;                                                       \
          pm = fmaxf(pm, v);                                                   \
        }                                                                      \
    }                                                                          \
    pm = fmaxf(pm, __shfl_xor(pm, 16));                                        \
    pm = fmaxf(pm, __shfl_xor(pm, 32));                                        \
    bool skip = (pm <= mrow + 8.0f);                                           \
    if (!__all(skip)) {                                                        \
      float mn = fmaxf(mrow, pm);                                              \
      float sc = exp2f((mrow - mn) * LOG2E);                                   \
      mrow = mn;                                                               \
      lsum *= sc;                                                              \
      _Pragma("unroll")                                                        \
      for (int nf = 0; nf < 16; ++nf)                                          \
        _Pragma("unroll")                                                      \
        for (int r = 0; r < 4; ++r) oacc[nf][r] *= sc;                         \
    }                                                                          \
    _Pragma("unroll")                                                          \
    for (int nf = 0; nf < 2; ++nf) {                                           \
      float p0 = exp2f((sv[nf][0] - mrow) * LOG2E);                            \
      float p1 = exp2f((sv[nf][1] - mrow) * LOG2E);                            \
      float p2 = exp2f((sv[nf][2] - mrow) * LOG2E);                            \
      float p3 = exp2f((sv[nf][3] - mrow) * LOG2E);                            \
      lsum += (p0 + p1) + (p2 + p3);                                           \
      uint64_t pk = (uint64_t)f2bf(p0) | ((uint64_t)f2bf(p1) << 16) |          \
                    ((uint64_t)f2bf(p2) << 32) | ((uint64_t)f2bf(p3) << 48);   \
      *(uint64_t*)&ldsP[w][lc * 36 + nf * 16 + lr * 4] = pk;                   \
    }                                                                          \
    if (j_ + 1 < nkv) {                                                        \
      N[0] = (f32x4){0.f, 0.f, 0.f, 0.f};                                      \
      N[1] = (f32x4){0.f, 0.f, 0.f, 0.f};                                      \
      __builtin_amdgcn_s_setprio(1);                                           \
      _Pragma("unroll")                                                        \
      for (int kb = 0; kb < 8; ++kb)                                           \
        _Pragma("unroll")                                                      \
        for (int nf = 0; nf < 2; ++nf) {                                       \
          bf16x8 kf =                                                          \
              *(bf16x8*)&ldsK[(j_ + 1) & 1][((kb * 2 + nf) * 64 + l) * 8];     \
          N[nf] = __builtin_amdgcn_mfma_f32_16x16x32_bf16(kf, qf[kb], N[nf],   \
                                                          0, 0, 0);            \
        }                                                                      \
      __builtin_amdgcn_s_setprio(0);                                           \
    }                                                                          \
    __syncthreads();                                                           \
    bf16x8 pf = *(bf16x8*)&ldsP[w][lc * 36 + lr * 8];                          \
    __builtin_amdgcn_s_setprio(1);                                             \
    _Pragma("unroll")                                                          \
    for (int nf = 0; nf < 16; ++nf)                                            \
      oacc[nf] =                                                               \
          __builtin_amdgcn_mfma_f32_16x16x32_bf16(vfr[nf], pf, oacc[nf],       \
                                                  0, 0, 0);                    \
    __builtin_amdgcn_s_setprio(0);                                             \
  }

  for (int kt = 0; kt < nkv; kt += 2) {
    SUBITER(kt, saccA, saccB);        // softmax(kt); QK(kt+1)->saccB (always)
    SUBITER(kt + 1, saccB, saccA);    // softmax(kt+1); QK(kt+2)->saccA if any
  }
#undef SUBITER

  // finalize (packed u64 stores: 4 consecutive j per r-group)
  float s = lsum;
  s += __shfl_xor(s, 16);
  s += __shfl_xor(s, 32);
  float inv = 1.0f / s;

  const int b = bh >> 1, h = bh & 1;
  if (qrow_l < S_) {
    int i = b * S_ + qrow_l;
    int it = i >> 7, mf = (i >> 4) & 7, li = i & 15;
#pragma unroll
    for (int nf = 0; nf < 16; ++nf) {
      int j0 = h * HD_ + nf * 16 + lr * 4;
      uint64_t pk = 0;
#pragma unroll
      for (int r = 0; r < 4; ++r)
        pk |= (uint64_t)f2bf(oacc[nf][r] * inv) << (16 * r);
      size_t addr = (((size_t)(it * 8 + (j0 >> 6))) * 16 + ((j0 >> 5) & 1) * 8 + mf) * 512 +
                    (((j0 >> 3) & 3) * 16 + li) * 8 + (j0 & 7);
      *(uint64_t*)&Obf[addr] = pk;
    }
  }
}

// ---------------------------------------------------------------------------
extern "C" void kernel_launch(void* const* d_in, const int* in_sizes, int n_in,
                              void* d_out, int out_size, void* d_ws, size_t ws_size,
                              hipStream_t stream) {
  const float* X    = (const float*)d_in[0];
  const float* Wqkv = (const float*)d_in[1];
  const float* bqkv = (const float*)d_in[2];
  const float* Wout = (const float*)d_in[3];
  const float* bout = (const float*)d_in[4];
  float* out = (float*)d_out;

  char* ws = (char*)d_ws;
  u16* Xf  = (u16*)ws;  ws += (size_t)MPAD * D_ * 2;
  u16* Wqf = (u16*)ws;  ws += (size_t)NQKV * D_ * 2;
  u16* Wof = (u16*)ws;  ws += (size_t)D_ * D_ * 2;
  u16* Qb  = (u16*)ws;  ws += (size_t)B_ * H_ * SPAD * HD_ * 2;
  u16* Kf  = (u16*)ws;  ws += (size_t)B_ * H_ * SPAD * HD_ * 2;
  u16* Vf  = (u16*)ws;  ws += (size_t)B_ * H_ * SPAD * HD_ * 2;
  u16* Obf = (u16*)ws;  ws += (size_t)MPAD * D_ * 2;
  // total ~101 MB

  convert_kernel<<<2048, 256, 0, stream>>>(X, Wqkv, Wout, Xf, Wqf, Wof);
  gemm_kernel<0><<<1800, 256, 0, stream>>>(Xf, Wqf, bqkv, 12, Qb, Kf, Vf, nullptr);
  attn_kernel<<<608, 256, 0, stream>>>(Qb, Kf, Vf, Obf);
  gemm_kernel<1><<<600, 256, 0, stream>>>(Obf, Wof, bout, 4, nullptr, nullptr, nullptr, out);
}

// Round 17
// 146.852 us; speedup vs baseline: 1.0884x; 1.0071x over previous
//
#include <hip/hip_runtime.h>
#include <stdint.h>

#define D_    512
#define H_    2
#define HD_   256
#define B_    16
#define S_    1194
#define MTOK  19104          // B_*S_  (even; batch boundaries at even i)
#define MPAD  19200          // 150*128
#define SPAD  1216           // 19*64 = 38*32
#define NQKV  1536
#define NKT   38             // kv tiles of 32 (global layout granularity)
#define LOG2E 1.44269504088896340736f

typedef unsigned short u16;
typedef unsigned int u32;
typedef __attribute__((ext_vector_type(8))) short bf16x8;   // 8 bf16 = 4 VGPR
typedef __attribute__((ext_vector_type(4))) float f32x4;

__device__ inline u16 f2bf(float x) {
  union { float f; unsigned u; } c; c.f = x;
  unsigned r = c.u + 0x7fffu + ((c.u >> 16) & 1u);  // RNE
  return (u16)(r >> 16);
}

// async global->LDS, 16B per lane. LDS dest is wave-uniform base (HW adds
// lane*16); global src per-lane, CONTIGUOUS: 1 instr = 1KB sequential.
__device__ inline void async_copy16(void* lds, const void* g) {
  __builtin_amdgcn_global_load_lds(
      (__attribute__((address_space(1))) void*)(g),
      (__attribute__((address_space(3))) void*)(lds),
      16, 0, 0);
}

// ---------------------------------------------------------------------------
// Kernel 1 (unchanged): X/W -> frag-major bf16.
// ---------------------------------------------------------------------------
__global__ void convert_kernel(const float* __restrict__ X,
                               const float* __restrict__ Wqkv,
                               const float* __restrict__ Wout,
                               u16* __restrict__ Xf,
                               u16* __restrict__ Wqf,
                               u16* __restrict__ Wof) {
  const int NXG = MPAD * 64;
  const int NQG = 12 * 8 * 16 * 64;
  const int NOG = 4 * 8 * 16 * 64;
  const int TOT = NXG + NQG + NOG;
  int stride = gridDim.x * blockDim.x;
  for (int g = blockIdx.x * blockDim.x + threadIdx.x; g < TOT; g += stride) {
    if (g < NXG) {
      int lane = g & 63, f = (g >> 6) & 15, kt = (g >> 10) & 7, mt = g >> 13;
      int i = mt * 128 + (f & 7) * 16 + (lane & 15);
      int k = kt * 64 + (f >> 3) * 32 + (lane >> 4) * 8;
      bf16x8 o;
      if (i < MTOK) {
        f32x4 v0 = *(const f32x4*)&X[(size_t)i * 512 + k];
        f32x4 v1 = *(const f32x4*)&X[(size_t)i * 512 + k + 4];
#pragma unroll
        for (int e = 0; e < 4; ++e) { o[e] = (short)f2bf(v0[e]); o[4 + e] = (short)f2bf(v1[e]); }
      } else {
#pragma unroll
        for (int e = 0; e < 8; ++e) o[e] = 0;
      }
      *(bf16x8*)&Xf[(size_t)g * 8] = o;
    } else if (g < NXG + NQG) {
      int gg = g - NXG;
      int lane = gg & 63, f = (gg >> 6) & 15, kt = (gg >> 10) & 7, nt = gg >> 13;
      int j = nt * 128 + (f & 7) * 16 + (lane & 15);
      int k = kt * 64 + (f >> 3) * 32 + (lane >> 4) * 8;
      bf16x8 o;
#pragma unroll
      for (int e = 0; e < 8; ++e) o[e] = (short)f2bf(Wqkv[(size_t)(k + e) * NQKV + j]);
      *(bf16x8*)&Wqf[(size_t)gg * 8] = o;
    } else {
      int gg = g - NXG - NQG;
      int lane = gg & 63, f = (gg >> 6) & 15, kt = (gg >> 10) & 7, nt = gg >> 13;
      int j = nt * 128 + (f & 7) * 16 + (lane & 15);
      int k = kt * 64 + (f >> 3) * 32 + (lane >> 4) * 8;
      bf16x8 o;
#pragma unroll
      for (int e = 0; e < 8; ++e) o[e] = (short)f2bf(Wout[(size_t)(k + e) * 512 + j]);
      *(bf16x8*)&Wof[(size_t)gg * 8] = o;
    }
  }
}

// ---------------------------------------------------------------------------
// GEMM v3 (unchanged from round 16): m97 schedule + vectorized epilogue.
// ---------------------------------------------------------------------------
template<int MODE>
__global__ __launch_bounds__(256, 2) void gemm_kernel(
    const u16* __restrict__ Af, const u16* __restrict__ Bf,
    const float* __restrict__ bias, int nb,
    u16* __restrict__ Qb, u16* __restrict__ Kf, u16* __restrict__ Vf,
    float* __restrict__ Cout)
{
  __shared__ u16 ldsA[16 * 512];       // 16 KiB (single buffer)
  __shared__ u16 ldsB[16 * 512];

  const int t  = threadIdx.x;
  const int l  = t & 63;
  const int w  = t >> 6;
  const int lr = l >> 4, lc = l & 15;

  const int nwg = gridDim.x;
  const int qq = nwg >> 3, rr8 = nwg & 7;
  const int xcd = blockIdx.x & 7, off = blockIdx.x >> 3;
  const int wgid = (xcd < rr8 ? xcd * (qq + 1) : rr8 * (qq + 1) + (xcd - rr8) * qq) + off;
  const int m0 = (wgid / nb) * 128;
  const int n0 = (wgid % nb) * 128;
  const bool vband = (MODE == 0) && ((wgid % nb) >= 8);

  const u16* pA = Af + ((size_t)(m0 >> 7) * 128 + w) * 512 + l * 8;
  const u16* pB = Bf + ((size_t)(n0 >> 7) * 128 + w) * 512 + l * 8;

  f32x4 acc[4][4] = {};

  for (int kt = 0; kt < 8; ++kt) {
    __syncthreads();                   // prev compute done: buffer reusable
    const u16* qA = pA + kt * 8192;
    const u16* qB = pB + kt * 8192;
#pragma unroll
    for (int c = 0; c < 4; ++c) {
      async_copy16(&ldsA[(c * 4 + w) * 512], qA + c * 2048);
      async_copy16(&ldsB[(c * 4 + w) * 512], qB + c * 2048);
    }
    __syncthreads();                   // stage landed (vmcnt drain)
#pragma unroll
    for (int kk = 0; kk < 2; ++kk) {
      bf16x8 af[4], bfr[4];
#pragma unroll
      for (int m = 0; m < 4; ++m)
        af[m] = *(bf16x8*)&ldsA[((kk * 8 + (w >> 1) * 4 + m) * 64 + l) * 8];
#pragma unroll
      for (int n = 0; n < 4; ++n)
        bfr[n] = *(bf16x8*)&ldsB[((kk * 8 + (w & 1) * 4 + n) * 64 + l) * 8];
      __builtin_amdgcn_s_setprio(1);
      if (!vband) {                    // swapped: D^T (lane = fixed token i)
#pragma unroll
        for (int m = 0; m < 4; ++m)
#pragma unroll
          for (int n = 0; n < 4; ++n)
            acc[m][n] = __builtin_amdgcn_mfma_f32_16x16x32_bf16(bfr[n], af[m], acc[m][n], 0, 0, 0);
      } else {                         // original: lane = fixed col j
#pragma unroll
        for (int m = 0; m < 4; ++m)
#pragma unroll
          for (int n = 0; n < 4; ++n)
            acc[m][n] = __builtin_amdgcn_mfma_f32_16x16x32_bf16(af[m], bfr[n], acc[m][n], 0, 0, 0);
      }
      __builtin_amdgcn_s_setprio(0);
    }
  }

  if (MODE == 1) {
#pragma unroll
    for (int m = 0; m < 4; ++m) {
      int i = m0 + (w >> 1) * 64 + m * 16 + lc;
      if (i >= MTOK) continue;
#pragma unroll
      for (int n = 0; n < 4; ++n) {
        int jb = n0 + (w & 1) * 64 + n * 16 + lr * 4;
        f32x4 bv = *(const f32x4*)&bias[jb];
        f32x4 o;
#pragma unroll
        for (int r = 0; r < 4; ++r) o[r] = acc[m][n][r] + bv[r];
        *(f32x4*)&Cout[(size_t)i * D_ + jb] = o;
      }
    }
  } else if (!vband) {
#pragma unroll
    for (int m = 0; m < 4; ++m) {
      int i = m0 + (w >> 1) * 64 + m * 16 + lc;
      if (i >= MTOK) continue;
      int b = i / S_, s = i - b * S_;
      int stK = s >> 5, nfs = (s >> 4) & 1, lisK = s & 15;
#pragma unroll
      for (int n = 0; n < 4; ++n) {
        int jb = n0 + (w & 1) * 64 + n * 16 + lr * 4;
        f32x4 bv = *(const f32x4*)&bias[jb];
        uint64_t pk = 0;
#pragma unroll
        for (int r = 0; r < 4; ++r)
          pk |= (uint64_t)f2bf(acc[m][n][r] + bv[r]) << (16 * r);
        int which = jb >> 9, h = (jb >> 8) & 1, d = jb & 255;
        int bh = b * H_ + h;
        if (which == 0) {
          *(uint64_t*)&Qb[(size_t)(bh * SPAD + s) * HD_ + d] = pk;
        } else {
          *(uint64_t*)&Kf[(((size_t)(bh * NKT + stK)) * 16 + (d >> 5) * 2 + nfs) * 512 +
                          (((d >> 3) & 3) * 16 + lisK) * 8 + (d & 7)] = pk;
        }
      }
    }
  } else {
    int jv[4]; float bj[4];
#pragma unroll
    for (int n = 0; n < 4; ++n) { jv[n] = n0 + (w & 1) * 64 + n * 16 + lc; bj[n] = bias[jv[n]]; }
#pragma unroll
    for (int m = 0; m < 4; ++m) {
#pragma unroll
      for (int rp = 0; rp < 4; rp += 2) {
        int i0 = m0 + (w >> 1) * 64 + m * 16 + lr * 4 + rp;   // even
        if (i0 >= MTOK) continue;                             // i0+1 < MTOK too
        int b = i0 / S_, s = i0 - b * S_;                     // pair same batch
        int stK = s >> 5, lvhi = (s >> 3) & 3, es = s & 7;    // es even
#pragma unroll
        for (int n = 0; n < 4; ++n) {
          int j = jv[n];
          int h = (j >> 8) & 1, d = j & 255;
          int bh = b * H_ + h;
          u32 pk = (u32)f2bf(acc[m][n][rp] + bj[n]) |
                   ((u32)f2bf(acc[m][n][rp + 1] + bj[n]) << 16);
          *(u32*)&Vf[(((size_t)(bh * NKT + stK)) * 16 + (d >> 4)) * 512 +
                     (lvhi * 16 + (d & 15)) * 8 + es] = pk;
        }
      }
    }
  }
}

// ---------------------------------------------------------------------------
// Kernel 3: causal flash attention v12 = v11 + V PREFETCH DISTANCE 1:
// V(j+1) loads issue right AFTER PV(j)'s MFMAs (vfr regs dead at PV issue;
// HW scoreboard handles WAR). Cover window: PV tail + all of subiter j+1 up
// to its barrier (~1500+ cyc) instead of softmax-only (~800). vfr persists
// across iterations; prologue loads V(0); guard j+1<nkv (Vf end, bh=31).
// Everything else byte-identical to round 16.
// ---------------------------------------------------------------------------
__global__ __launch_bounds__(256, 2) void attn_kernel(
    const u16* __restrict__ Qb, const u16* __restrict__ Kf,
    const u16* __restrict__ Vf, u16* __restrict__ Obf)
{
  __shared__ u16 ldsK[2][16 * 512];     // 2 x 16 KiB, frag = kb*2+nf
  __shared__ u16 ldsP[4][16 * 36];      // per-wave P [16 q][32 kv], pad 36

  const int id   = blockIdx.x;          // 0..607
  const int xcd  = id & 7;
  const int slot = id >> 3;             // 0..75
  const int bh   = xcd + 8 * (slot / 19);
  const int qt   = 18 - (slot % 19);    // long blocks first
  const int q0   = qt * 64;
  const int nkv  = 2 * qt + 2;          // kv tiles of 32 (ALWAYS EVEN)
  const int t  = threadIdx.x, l = t & 63, w = t >> 6;
  const int lr = l >> 4, lc = l & 15;
  const int wq0 = q0 + w * 16;          // wave's first q row
  const int qrow_l = wq0 + lc;          // THIS lane's q row (swapped space)

  // Q fragments (B-operand rows=q over d): 8 d-blocks of 32
  bf16x8 qf[8];
  const u16* qbase = Qb + (size_t)(bh * SPAD + qrow_l) * HD_ + lr * 8;
#pragma unroll
  for (int kb = 0; kb < 8; ++kb)
    qf[kb] = *(const bf16x8*)(qbase + kb * 32);

  f32x4 oacc[16] = {};                  // [d-block]; col=q=lc, reg=d-sub
  float mrow = -1e30f, lsum = 0.f;      // per-lane scalars (q = lc)

  const u16* kroot = Kf + ((size_t)(bh * NKT) * 16 + w) * 512 + l * 8;
  const u16* vroot = Vf + ((size_t)(bh * NKT) * 16) * 512 + l * 8;

  // prologue: stage K(0)->buf0, K(1)->buf1; load V(0) to registers
#pragma unroll
  for (int c = 0; c < 4; ++c) {
    async_copy16(&ldsK[0][(c * 4 + w) * 512], kroot + c * 2048);
    async_copy16(&ldsK[1][(c * 4 + w) * 512], kroot + 8192 + c * 2048);
  }
  bf16x8 vfr[16];
#pragma unroll
  for (int f = 0; f < 16; ++f) vfr[f] = *(const bf16x8*)(vroot + f * 512);
  __syncthreads();

  f32x4 saccA[2] = {}, saccB[2] = {};
  // QK(0) -> saccA
  __builtin_amdgcn_s_setprio(1);
#pragma unroll
  for (int kb = 0; kb < 8; ++kb)
#pragma unroll
    for (int nf = 0; nf < 2; ++nf) {
      bf16x8 kf = *(bf16x8*)&ldsK[0][((kb * 2 + nf) * 64 + l) * 8];
      saccA[nf] = __builtin_amdgcn_mfma_f32_16x16x32_bf16(kf, qf[kb], saccA[nf], 0, 0, 0);
    }
  __builtin_amdgcn_s_setprio(0);
  __syncthreads();   // all waves past QK(0) before buf0 is restaged in sub-iter 0

  // SUBITER(j, S, N): stage K(j+2)->buf[j&1]; softmax(j) on S; QK(j+1)->N;
  // barrier; PV(j) using vfr (loaded last iter); load V(j+1)->vfr.
#define SUBITER(J, S, N)                                                       \
  {                                                                            \
    const int j_ = (J);                                                        \
    if (j_ + 2 < nkv) {                                                        \
      const u16* kb_ = kroot + (size_t)(j_ + 2) * 8192;                        \
      _Pragma("unroll")                                                        \
      for (int c = 0; c < 4; ++c)                                              \
        async_copy16(&ldsK[j_ & 1][(c * 4 + w) * 512], kb_ + c * 2048);        \
    }                                                                          \
    const int kv0 = j_ * 32;                                                   \
    float sv[2][4];                                                            \
    float pm = -1e30f;                                                         \
    if (kv0 + 31 <= wq0) {                                                     \
      _Pragma("unroll")                                                        \
      for (int nf = 0; nf < 2; ++nf)                                           \
        _Pragma("unroll")                                                      \
        for (int r = 0; r < 4; ++r) {                                          \
          float v = S[nf][r] * 0.0625f;                                        \
          sv[nf][r] = v;                                                       \
          pm = fmaxf(pm, v);                                                   \
        }                                                                      \
    } else {                                                                   \
      _Pragma("unroll")                                                        \
      for (int nf = 0; nf < 2; ++nf)                                           \
        _Pragma("unroll")                                                      \
        for (int r = 0; r < 4; ++r) {                                          \
          int kvi = kv0 + nf * 16 + lr * 4 + r;                                \
          float v = ((kvi <= qrow_l) && (kvi < S_)) ? S[nf][r] * 0.0625f       \
                                                    : -1e30f;                  \
          sv[nf][r] = v;                                                       \
          pm = fmaxf(pm, v);                                                   \
        }                                                                      \
    }                                                                          \
    pm = fmaxf(pm, __shfl_xor(pm, 16));                                        \
    pm = fmaxf(pm, __shfl_xor(pm, 32));                                        \
    bool skip = (pm <= mrow + 8.0f);                                           \
    if (!__all(skip)) {                                                        \
      float mn = fmaxf(mrow, pm);                                              \
      float sc = exp2f((mrow - mn) * LOG2E);                                   \
      mrow = mn;                                                               \
      lsum *= sc;                                                              \
      _Pragma("unroll")                                                        \
      for (int nf = 0; nf < 16; ++nf)                                          \
        _Pragma("unroll")                                                      \
        for (int r = 0; r < 4; ++r) oacc[nf][r] *= sc;                         \
    }                                                                          \
    _Pragma("unroll")                                                          \
    for (int nf = 0; nf < 2; ++nf) {                                           \
      float p0 = exp2f((sv[nf][0] - mrow) * LOG2E);                            \
      float p1 = exp2f((sv[nf][1] - mrow) * LOG2E);                            \
      float p2 = exp2f((sv[nf][2] - mrow) * LOG2E);                            \
      float p3 = exp2f((sv[nf][3] - mrow) * LOG2E);                            \
      lsum += (p0 + p1) + (p2 + p3);                                           \
      uint64_t pk = (uint64_t)f2bf(p0) | ((uint64_t)f2bf(p1) << 16) |          \
                    ((uint64_t)f2bf(p2) << 32) | ((uint64_t)f2bf(p3) << 48);   \
      *(uint64_t*)&ldsP[w][lc * 36 + nf * 16 + lr * 4] = pk;                   \
    }                                                                          \
    if (j_ + 1 < nkv) {                                                        \
      N[0] = (f32x4){0.f, 0.f, 0.f, 0.f};                                      \
      N[1] = (f32x4){0.f, 0.f, 0.f, 0.f};                                      \
      __builtin_amdgcn_s_setprio(1);                                           \
      _Pragma("unroll")                                                        \
      for (int kb = 0; kb < 8; ++kb)                                           \
        _Pragma("unroll")                                                      \
        for (int nf = 0; nf < 2; ++nf) {                                       \
          bf16x8 kf =                                                          \
              *(bf16x8*)&ldsK[(j_ + 1) & 1][((kb * 2 + nf) * 64 + l) * 8];     \
          N[nf] = __builtin_amdgcn_mfma_f32_16x16x32_bf16(kf, qf[kb], N[nf],   \
                                                          0, 0, 0);            \
        }                                                                      \
      __builtin_amdgcn_s_setprio(0);                                           \
    }                                                                          \
    __syncthreads();                                                           \
    bf16x8 pf = *(bf16x8*)&ldsP[w][lc * 36 + lr * 8];                          \
    __builtin_amdgcn_s_setprio(1);                                             \
    _Pragma("unroll")                                                          \
    for (int nf = 0; nf < 16; ++nf)                                            \
      oacc[nf] =                                                               \
          __builtin_amdgcn_mfma_f32_16x16x32_bf16(vfr[nf], pf, oacc[nf],       \
                                                  0, 0, 0);                    \
    __builtin_amdgcn_s_setprio(0);                                             \
    if (j_ + 1 < nkv) {                                                        \
      const u16* vb_ = vroot + (size_t)(j_ + 1) * 8192;                        \
      _Pragma("unroll")                                                        \
      for (int f = 0; f < 16; ++f) vfr[f] = *(const bf16x8*)(vb_ + f * 512);   \
    }                                                                          \
  }

  for (int kt = 0; kt < nkv; kt += 2) {
    SUBITER(kt, saccA, saccB);        // softmax(kt); QK(kt+1)->saccB (always)
    SUBITER(kt + 1, saccB, saccA);    // softmax(kt+1); QK(kt+2)->saccA if any
  }
#undef SUBITER

  // finalize (packed u64 stores: 4 consecutive j per r-group)
  float s = lsum;
  s += __shfl_xor(s, 16);
  s += __shfl_xor(s, 32);
  float inv = 1.0f / s;

  const int b = bh >> 1, h = bh & 1;
  if (qrow_l < S_) {
    int i = b * S_ + qrow_l;
    int it = i >> 7, mf = (i >> 4) & 7, li = i & 15;
#pragma unroll
    for (int nf = 0; nf < 16; ++nf) {
      int j0 = h * HD_ + nf * 16 + lr * 4;
      uint64_t pk = 0;
#pragma unroll
      for (int r = 0; r < 4; ++r)
        pk |= (uint64_t)f2bf(oacc[nf][r] * inv) << (16 * r);
      size_t addr = (((size_t)(it * 8 + (j0 >> 6))) * 16 + ((j0 >> 5) & 1) * 8 + mf) * 512 +
                    (((j0 >> 3) & 3) * 16 + li) * 8 + (j0 & 7);
      *(uint64_t*)&Obf[addr] = pk;
    }
  }
}

// ---------------------------------------------------------------------------
extern "C" void kernel_launch(void* const* d_in, const int* in_sizes, int n_in,
                              void* d_out, int out_size, void* d_ws, size_t ws_size,
                              hipStream_t stream) {
  const float* X    = (const float*)d_in[0];
  const float* Wqkv = (const float*)d_in[1];
  const float* bqkv = (const float*)d_in[2];
  const float* Wout = (const float*)d_in[3];
  const float* bout = (const float*)d_in[4];
  float* out = (float*)d_out;

  char* ws = (char*)d_ws;
  u16* Xf  = (u16*)ws;  ws += (size_t)MPAD * D_ * 2;
  u16* Wqf = (u16*)ws;  ws += (size_t)NQKV * D_ * 2;
  u16* Wof = (u16*)ws;  ws += (size_t)D_ * D_ * 2;
  u16* Qb  = (u16*)ws;  ws += (size_t)B_ * H_ * SPAD * HD_ * 2;
  u16* Kf  = (u16*)ws;  ws += (size_t)B_ * H_ * SPAD * HD_ * 2;
  u16* Vf  = (u16*)ws;  ws += (size_t)B_ * H_ * SPAD * HD_ * 2;
  u16* Obf = (u16*)ws;  ws += (size_t)MPAD * D_ * 2;
  // total ~101 MB

  convert_kernel<<<2048, 256, 0, stream>>>(X, Wqkv, Wout, Xf, Wqf, Wof);
  gemm_kernel<0><<<1800, 256, 0, stream>>>(Xf, Wqf, bqkv, 12, Qb, Kf, Vf, nullptr);
  attn_kernel<<<608, 256, 0, stream>>>(Qb, Kf, Vf, Obf);
  gemm_kernel<1><<<600, 256, 0, stream>>>(Obf, Wof, bout, 4, nullptr, nullptr, nullptr, out);
}